// Round 3
// baseline (82.469 us; speedup 1.0000x reference)
//
#include <hip/hip_runtime.h>
#include <hip/hip_bf16.h>

#define N1    2001
#define EMB   64
#define NSHOW 5
#define MSONG 25
#define NPOS  (NSHOW * MSONG)   // 125
#define MAXU  128

__global__ __launch_bounds__(256)
void setsgnn_kernel(
    const int* __restrict__ song_ids,
    const int* __restrict__ prev_setlists,
    const int* __restrict__ venue_ids,
    const int* __restrict__ tour_ids,
    const int* __restrict__ country_ids,
    const int* __restrict__ is_festival,
    const int* __restrict__ is_marathon,
    const float* __restrict__ song_emb,
    const float* __restrict__ gcn_w1, const float* __restrict__ gcn_b1,
    const float* __restrict__ gcn_w2, const float* __restrict__ gcn_b2,
    const float* __restrict__ q_w,  const float* __restrict__ q_b,
    const float* __restrict__ k_w,  const float* __restrict__ k_b,
    const float* __restrict__ v_w,  const float* __restrict__ v_b,
    const float* __restrict__ venue_t, const float* __restrict__ tour_t,
    const float* __restrict__ country_t, const float* __restrict__ fest_t,
    const float* __restrict__ mara_t,
    const float* __restrict__ ctx_w, const float* __restrict__ ctx_b,
    const float* __restrict__ p1_w,  const float* __restrict__ p1_b,
    const float* __restrict__ p2_w,  const float* __restrict__ p2_b,
    const float* __restrict__ p3_w,  const float* __restrict__ p3_b,
    float* __restrict__ out)
{
    const int b   = blockIdx.x;
    const int tid = threadIdx.x;
    const int wv   = tid >> 6;
    const int lane = tid & 63;

    __shared__ __align__(16) float xb0[MAXU][EMB];  // x_in (then x_out)
    __shared__ __align__(16) float xb1[MAXU][EMB];  // agg accumulation
    __shared__ unsigned short idmap[N1];            // song id -> compact idx (0xFFFF = absent)
    __shared__ int   list_ids[MAXU];
    __shared__ int   sl[NPOS];
    __shared__ int   pmap[NPOS];
    __shared__ float rs[MAXU];
    __shared__ float Xsum[NSHOW][EMB];
    __shared__ int   cnt_show[NSHOW];
    __shared__ int   U_cnt;
    __shared__ float show_e[NSHOW][EMB];
    __shared__ float ctxin[56];
    __shared__ float ctxv[EMB];
    __shared__ float qv[EMB];
    __shared__ float kv[NSHOW][EMB];
    __shared__ float vvv[NSHOW][EMB];
    __shared__ float attnw[NSHOW];
    __shared__ float hbuf[3 * EMB];
    __shared__ float h1b[128];
    __shared__ float h2b[64];

    // ---- Phase A: init map, load setlist ----
    for (int i = tid; i < N1; i += 256) idmap[i] = 0xFFFFu;
    for (int i = tid; i < NPOS; i += 256) sl[i] = prev_setlists[b * NPOS + i];
    if (tid == 0) U_cnt = 0;
    __syncthreads();

    // ---- Phase B: mark active ids (setlist ids > 0, plus candidate) ----
    for (int i = tid; i < NPOS; i += 256) { int id = sl[i]; if (id > 0) idmap[id] = 1u; }
    if (tid == 0) idmap[song_ids[b]] = 1u;
    __syncthreads();

    // ---- Phase C: compact (order irrelevant) ----
    for (int i = tid; i < N1; i += 256) {
        if (idmap[i] == 1u) {
            int u = atomicAdd(&U_cnt, 1);
            idmap[i] = (unsigned short)u;
            list_ids[u] = i;
        }
    }
    __syncthreads();
    const int U = U_cnt;   // <= 126

    // ---- Phase D: per-show counts, position map, row sums ----
    for (int i = tid; i < MAXU; i += 256) rs[i] = 0.f;
    if (tid < NSHOW) {
        int c = 0;
        for (int i = 0; i < MSONG; i++) c += (sl[tid * MSONG + i] > 0) ? 1 : 0;
        cnt_show[tid] = c;
    }
    __syncthreads();
    for (int i = tid; i < NPOS; i += 256) {
        int id = sl[i];
        int pm = (id > 0) ? (int)idmap[id] : -1;
        pmap[i] = pm;
        if (pm >= 0) atomicAdd(&rs[pm], (float)(cnt_show[i / MSONG] - 1));
    }
    // ---- Phase E: gather x0 rows (song_emb), vectorized ----
    for (int t = tid; t < U * (EMB / 4); t += 256) {
        int u = t >> 4, e4 = t & 15;
        const float4 v = *(const float4*)&song_emb[list_ids[u] * EMB + e4 * 4];
        *(float4*)&xb0[u][e4 * 4] = v;
    }
    __syncthreads();

    // ---- GCN layers ----
    const float* wptrs[2] = { gcn_w1, gcn_w2 };
    const float* bptrs[2] = { gcn_b1, gcn_b2 };
    for (int layer = 0; layer < 2; ++layer) {
        const float* wp = wptrs[layer];
        const float* bp = bptrs[layer];

        // zero agg buffer
        for (int t = tid; t < U * EMB; t += 256) xb1[t >> 6][t & 63] = 0.f;
        __syncthreads();

        // Xsum[s][e] = sum over valid positions of x_in[pmap][e]
        for (int t = tid; t < NSHOW * EMB; t += 256) {
            int s = t >> 6, e = t & 63;
            float acc = 0.f;
            for (int i = 0; i < MSONG; i++) {
                int pm = pmap[s * MSONG + i];
                if (pm >= 0) acc += xb0[pm][e];
            }
            Xsum[s][e] = acc;
        }
        __syncthreads();

        // scatter: agg[u] += (Xsum_s - x_in[u]) per occurrence
        for (int t = tid; t < NPOS * EMB; t += 256) {
            int pos = t >> 6, e = t & 63;
            int pm = pmap[pos];
            if (pm >= 0)
                atomicAdd(&xb1[pm][e], Xsum[pos / MSONG][e] - xb0[pm][e]);
        }
        __syncthreads();

        // matmul + bias + relu: x_out[u][lane] = relu((agg[u]/(rs[u]+1e-10)) @ W + b)
        // lane = output column; weight column cached in registers (64 VGPRs)
        float wcol[EMB];
        #pragma unroll
        for (int e = 0; e < EMB; e++) wcol[e] = wp[e * EMB + lane];
        const float bias = bp[lane];
        for (int u = wv; u < U; u += 4) {
            float inv = 1.f / (rs[u] + 1e-10f);
            float a0 = 0.f, a1 = 0.f, a2 = 0.f, a3 = 0.f;
            #pragma unroll
            for (int e = 0; e < EMB; e += 4) {
                const float4 a = *(const float4*)&xb1[u][e];
                a0 += a.x * wcol[e];
                a1 += a.y * wcol[e + 1];
                a2 += a.z * wcol[e + 2];
                a3 += a.w * wcol[e + 3];
            }
            float val = ((a0 + a1) + (a2 + a3)) * inv + bias;
            xb0[u][lane] = val > 0.f ? val : 0.f;
        }
        __syncthreads();
    }

    // ---- show embeddings: masked mean of x2 ----
    for (int t = tid; t < NSHOW * EMB; t += 256) {
        int s = t >> 6, e = t & 63;
        float acc = 0.f;
        for (int i = 0; i < MSONG; i++) {
            int pm = pmap[s * MSONG + i];
            if (pm >= 0) acc += xb0[pm][e];
        }
        int c = cnt_show[s];
        show_e[s][e] = (c > 0) ? acc / (float)c : 0.f;
    }
    // ---- ctx input concat ----
    if (tid < 16)       ctxin[tid] = venue_t[venue_ids[b] * 16 + tid];
    else if (tid < 32)  ctxin[tid] = tour_t[tour_ids[b] * 16 + (tid - 16)];
    else if (tid < 40)  ctxin[tid] = country_t[country_ids[b] * 8 + (tid - 32)];
    else if (tid < 48)  ctxin[tid] = fest_t[is_festival[b] * 8 + (tid - 40)];
    else if (tid < 56)  ctxin[tid] = mara_t[is_marathon[b] * 8 + (tid - 48)];
    __syncthreads();

    // ctx = ctxin @ ctx_w + ctx_b
    if (tid < EMB) {
        float acc = 0.f;
        for (int e = 0; e < 56; e++) acc += ctxin[e] * ctx_w[e * EMB + tid];
        ctxv[tid] = acc + ctx_b[tid];
    }
    __syncthreads();

    // q = ctx @ q_w + q_b
    if (tid < EMB) {
        float acc = 0.f;
        for (int e = 0; e < EMB; e++) acc += ctxv[e] * q_w[e * EMB + tid];
        qv[tid] = acc + q_b[tid];
    }
    // k, v = show_e @ {k_w,v_w} + bias   (640 tasks)
    for (int t = tid; t < 2 * NSHOW * EMB; t += 256) {
        int which = (t >= NSHOW * EMB) ? 1 : 0;
        int tt = which ? t - NSHOW * EMB : t;
        int s = tt >> 6, eo = tt & 63;
        const float* wp = which ? v_w : k_w;
        float acc = 0.f;
        for (int e = 0; e < EMB; e++) acc += show_e[s][e] * wp[e * EMB + eo];
        acc += which ? v_b[eo] : k_b[eo];
        if (which) vvv[s][eo] = acc; else kv[s][eo] = acc;
    }
    __syncthreads();

    // scores
    if (tid < NSHOW) {
        float acc = 0.f;
        for (int e = 0; e < EMB; e++) acc += qv[e] * kv[tid][e];
        attnw[tid] = acc * 0.125f;   // 1/sqrt(64)
    }
    __syncthreads();
    // softmax over 5 (thread 0)
    if (tid == 0) {
        float mx = attnw[0];
        for (int s = 1; s < NSHOW; s++) mx = fmaxf(mx, attnw[s]);
        float sum = 0.f;
        for (int s = 0; s < NSHOW; s++) { float ev = expf(attnw[s] - mx); attnw[s] = ev; sum += ev; }
        float isum = 1.f / sum;
        for (int s = 0; s < NSHOW; s++) attnw[s] *= isum;
    }
    __syncthreads();

    // attended + concat h = [cand, ctx, attended]
    if (tid < EMB) {
        float acc = 0.f;
        for (int s = 0; s < NSHOW; s++) acc += attnw[s] * vvv[s][tid];
        hbuf[2 * EMB + tid] = acc;
        hbuf[EMB + tid] = ctxv[tid];
        int uc = (int)idmap[song_ids[b]];
        hbuf[tid] = xb0[uc][tid];
    }
    __syncthreads();

    // p1: 192 -> 128, relu
    if (tid < 128) {
        float acc = 0.f;
        for (int e = 0; e < 192; e++) acc += hbuf[e] * p1_w[e * 128 + tid];
        acc += p1_b[tid];
        h1b[tid] = acc > 0.f ? acc : 0.f;
    }
    __syncthreads();

    // p2: 128 -> 64, relu
    if (tid < 64) {
        float acc = 0.f;
        for (int e = 0; e < 128; e++) acc += h1b[e] * p2_w[e * 64 + tid];
        acc += p2_b[tid];
        h2b[tid] = acc > 0.f ? acc : 0.f;
    }
    __syncthreads();

    // p3: 64 -> 1, sigmoid
    if (tid == 0) {
        float acc = 0.f;
        for (int e = 0; e < EMB; e++) acc += h2b[e] * p3_w[e];
        acc += p3_b[0];
        out[b] = 1.f / (1.f + expf(-acc));
    }
}

extern "C" void kernel_launch(void* const* d_in, const int* in_sizes, int n_in,
                              void* d_out, int out_size, void* d_ws, size_t ws_size,
                              hipStream_t stream) {
    (void)n_in; (void)out_size; (void)d_ws; (void)ws_size;
    const int B = in_sizes[0];
    setsgnn_kernel<<<B, 256, 0, stream>>>(
        (const int*)d_in[0], (const int*)d_in[1], (const int*)d_in[2],
        (const int*)d_in[3], (const int*)d_in[4], (const int*)d_in[5],
        (const int*)d_in[6],
        (const float*)d_in[7],
        (const float*)d_in[8],  (const float*)d_in[9],
        (const float*)d_in[10], (const float*)d_in[11],
        (const float*)d_in[12], (const float*)d_in[13],
        (const float*)d_in[14], (const float*)d_in[15],
        (const float*)d_in[16], (const float*)d_in[17],
        (const float*)d_in[18], (const float*)d_in[19],
        (const float*)d_in[20], (const float*)d_in[21],
        (const float*)d_in[22],
        (const float*)d_in[23], (const float*)d_in[24],
        (const float*)d_in[25], (const float*)d_in[26],
        (const float*)d_in[27], (const float*)d_in[28],
        (const float*)d_in[29], (const float*)d_in[30],
        (float*)d_out);
}

// Round 4
// 36.339 us; speedup vs baseline: 2.2694x; 2.2694x over previous
//
#include <hip/hip_runtime.h>
#include <hip/hip_bf16.h>

#define N1    2001
#define EMB   64
#define NSHOW 5
#define MSONG 25
#define NPOS  (NSHOW * MSONG)   // 125
#define MAXU  128
#define NT    1024

__global__ __launch_bounds__(NT)
void setsgnn_kernel(
    const int* __restrict__ song_ids,
    const int* __restrict__ prev_setlists,
    const int* __restrict__ venue_ids,
    const int* __restrict__ tour_ids,
    const int* __restrict__ country_ids,
    const int* __restrict__ is_festival,
    const int* __restrict__ is_marathon,
    const float* __restrict__ song_emb,
    const float* __restrict__ gcn_w1, const float* __restrict__ gcn_b1,
    const float* __restrict__ gcn_w2, const float* __restrict__ gcn_b2,
    const float* __restrict__ q_w,  const float* __restrict__ q_b,
    const float* __restrict__ k_w,  const float* __restrict__ k_b,
    const float* __restrict__ v_w,  const float* __restrict__ v_b,
    const float* __restrict__ venue_t, const float* __restrict__ tour_t,
    const float* __restrict__ country_t, const float* __restrict__ fest_t,
    const float* __restrict__ mara_t,
    const float* __restrict__ ctx_w, const float* __restrict__ ctx_b,
    const float* __restrict__ p1_w,  const float* __restrict__ p1_b,
    const float* __restrict__ p2_w,  const float* __restrict__ p2_b,
    const float* __restrict__ p3_w,  const float* __restrict__ p3_b,
    float* __restrict__ out)
{
    const int b    = blockIdx.x;
    const int tid  = threadIdx.x;
    const int wv   = tid >> 6;
    const int lane = tid & 63;

    __shared__ __align__(16) float xb0[MAXU][EMB];       // 32 KB
    __shared__ __align__(16) float xb1[MAXU][EMB];       // 32 KB
    __shared__ __align__(16) float wlds[2][EMB][EMB];    // 32 KB: gcn_w1/w2, later k_w/v_w
    __shared__ __align__(16) float blds[2][EMB];
    __shared__ unsigned short idmap[N1];
    __shared__ int   sl[NPOS];
    __shared__ int   pmap[NPOS];
    __shared__ int   list_ids[MAXU];
    __shared__ float c_us[MAXU][NSHOW];   // per-(node,show) occurrence counts
    __shared__ float occv[MAXU];
    __shared__ float invv[MAXU];
    __shared__ float cntm1[NSHOW];
    __shared__ int   cnt_show[NSHOW];
    __shared__ int   U_cnt;
    __shared__ float Xsum[NSHOW][EMB];
    __shared__ float XW[NSHOW][EMB];
    __shared__ float show_e[NSHOW][EMB];
    __shared__ float ctxin[56];
    __shared__ float ctxv[EMB];
    __shared__ float qv[EMB];
    __shared__ float kvatt[NSHOW][EMB];
    __shared__ float vatt[NSHOW][EMB];
    __shared__ float attnw[NSHOW];
    __shared__ float hbuf[3 * EMB];
    __shared__ float h1b[128];
    __shared__ float h2b[EMB];
    __shared__ float partial[1024];

    // ---- issue long-latency loads FIRST (consumed much later -> hidden) ----
    const float4 g0 = ((const float4*)gcn_w1)[tid];   // 4096 floats = 1024 float4
    const float4 g1 = ((const float4*)gcn_w2)[tid];
    float4 bb;
    if (tid < 32) bb = (tid < 16) ? ((const float4*)gcn_b1)[tid]
                                  : ((const float4*)gcn_b2)[tid - 16];
    const int sid    = song_ids[b];
    const int vid    = venue_ids[b];
    const int tourid = tour_ids[b];
    const int cid    = country_ids[b];
    const int fid    = is_festival[b];
    const int mid    = is_marathon[b];

    // ---- Phase A: idmap init, setlist load, stage weights into LDS ----
    for (int i = tid; i < N1; i += NT) idmap[i] = 0xFFFFu;
    if (tid < NPOS) sl[tid] = prev_setlists[b * NPOS + tid];
    if (tid == 0) U_cnt = 0;
    ((float4*)wlds)[tid]      = g0;     // wlds[0] = gcn_w1
    ((float4*)wlds)[NT + tid] = g1;     // wlds[1] = gcn_w2
    if (tid < 32) ((float4*)blds)[tid] = bb;
    __syncthreads();

    // ---- Phase B: mark active ids ----
    if (tid < NPOS) { int id = sl[tid]; if (id > 0) idmap[id] = 1u; }
    if (tid == 0) idmap[sid] = 1u;
    __syncthreads();

    // ---- Phase C: compact ----
    for (int i = tid; i < N1; i += NT) {
        if (idmap[i] == 1u) {
            int u = atomicAdd(&U_cnt, 1);
            idmap[i] = (unsigned short)u;
            list_ids[u] = i;
        }
    }
    __syncthreads();
    const int U = U_cnt;   // <= 126

    // ---- Phase D: pmap, zero c, cnt_show ----
    if (tid < NPOS) { int id = sl[tid]; pmap[tid] = (id > 0) ? (int)idmap[id] : -1; }
    for (int t = tid; t < MAXU * NSHOW; t += NT) ((float*)c_us)[t] = 0.f;
    if (tid < NSHOW) {
        int c = 0;
        for (int i = 0; i < MSONG; i++) c += (sl[tid * MSONG + i] > 0) ? 1 : 0;
        cnt_show[tid] = c; cntm1[tid] = (float)(c - 1);
    }
    __syncthreads();

    // ---- Phase D2: build c; gather x0 rows (zero-fill unused rows) ----
    if (tid < NPOS) { int pm = pmap[tid]; if (pm >= 0) atomicAdd(&c_us[pm][tid / MSONG], 1.f); }
    for (int t = tid; t < MAXU * (EMB / 4); t += NT) {
        int u = t >> 4, e4 = t & 15;
        float4 v = make_float4(0.f, 0.f, 0.f, 0.f);
        if (u < U) v = ((const float4*)(song_emb + list_ids[u] * EMB))[e4];
        *(float4*)&xb0[u][e4 * 4] = v;
    }
    __syncthreads();

    // ---- Phase D3: occ/inv per node; ctxin gather ----
    if (tid < MAXU) {
        float o = 0.f, r = 0.f;
        #pragma unroll
        for (int s = 0; s < NSHOW; s++) { float cc = c_us[tid][s]; o += cc; r += cc * cntm1[s]; }
        occv[tid] = o; invv[tid] = 1.f / (r + 1e-10f);
    }
    {
        int e = tid - MAXU;    // threads 128..183
        if (e >= 0 && e < 56) {
            float val;
            if (e < 16)      val = venue_t[vid * 16 + e];
            else if (e < 32) val = tour_t[tourid * 16 + (e - 16)];
            else if (e < 40) val = country_t[cid * 8 + (e - 32)];
            else if (e < 48) val = fest_t[fid * 8 + (e - 40)];
            else             val = mara_t[mid * 8 + (e - 48)];
            ctxin[e] = val;
        }
    }
    __syncthreads();

    // ---- CTX: ctx = ctxin @ ctx_w + ctx_b ----
    if (tid < EMB) {
        float acc = ctx_b[tid];
        #pragma unroll
        for (int e = 0; e < 56; e++) acc += ctxin[e] * ctx_w[e * EMB + tid];
        ctxv[tid] = acc;
    }
    __syncthreads();

    // ---- Q (wave 0) + Xsum layer0 (waves 1..5) ----
    if (tid < EMB) {
        float acc = q_b[tid];
        #pragma unroll
        for (int e = 0; e < EMB; e++) acc += ctxv[e] * q_w[e * EMB + tid];
        qv[tid] = acc;
    }
    if (tid >= EMB && tid < EMB + NSHOW * EMB) {
        int t = tid - EMB, s = t >> 6, e = t & 63;
        float acc = 0.f;
        #pragma unroll
        for (int i = 0; i < MSONG; i++) { int pm = pmap[s * MSONG + i]; if (pm >= 0) acc += xb0[pm][e]; }
        Xsum[s][e] = acc;
    }
    __syncthreads();

    // ---- GCN layers (no adjacency, no atomics): ----
    // out[u][col] = relu( (Sum_s c[u][s]*XW[s][col] - occ[u]*(x[u]@W)[col]) * inv[u] + b[col] )
    float wcol[EMB];
    for (int l = 0; l < 2; ++l) {
        float (*xc)[EMB] = l ? xb1 : xb0;
        float (*xn)[EMB] = l ? xb0 : xb1;

        // wcol: this lane's weight column from LDS (conflict-free, e-major)
        #pragma unroll
        for (int e = 0; e < EMB; e++) wcol[e] = wlds[l][e][lane];
        // XW[s][col] = Xsum[s] @ W
        if (tid < NSHOW * EMB) {
            int s = tid >> 6, col = tid & 63;
            float acc = 0.f;
            #pragma unroll
            for (int e = 0; e < EMB; e++) acc += Xsum[s][e] * wlds[l][e][col];
            XW[s][col] = acc;
        }
        const float bias = blds[l][lane];
        __syncthreads();   // XW ready; wlds[l] fully consumed

        // layer 1: issue k_w/v_w restage loads now (written after the u-loop)
        float4 kreg, vreg;
        if (l == 1) { kreg = ((const float4*)k_w)[tid]; vreg = ((const float4*)v_w)[tid]; }

        for (int u = wv; u < U; u += 16) {
            float a0 = 0.f, a1 = 0.f, a2 = 0.f, a3 = 0.f;
            #pragma unroll
            for (int e4 = 0; e4 < 16; e4++) {
                const float4 a = *(const float4*)&xc[u][e4 * 4];
                a0 += a.x * wcol[e4 * 4];
                a1 += a.y * wcol[e4 * 4 + 1];
                a2 += a.z * wcol[e4 * 4 + 2];
                a3 += a.w * wcol[e4 * 4 + 3];
            }
            float y   = (a0 + a1) + (a2 + a3);
            float acc = c_us[u][0] * XW[0][lane] + c_us[u][1] * XW[1][lane]
                      + c_us[u][2] * XW[2][lane] + c_us[u][3] * XW[3][lane]
                      + c_us[u][4] * XW[4][lane];
            float val = (acc - occv[u] * y) * invv[u] + bias;
            xn[u][lane] = fmaxf(val, 0.f);
        }
        if (l == 1) { ((float4*)wlds)[tid] = kreg; ((float4*)wlds)[NT + tid] = vreg; }
        __syncthreads();

        if (l == 0) {   // Xsum for layer 1 from xb1
            if (tid < NSHOW * EMB) {
                int s = tid >> 6, e = tid & 63;
                float acc = 0.f;
                #pragma unroll
                for (int i = 0; i < MSONG; i++) { int pm = pmap[s * MSONG + i]; if (pm >= 0) acc += xb1[pm][e]; }
                Xsum[s][e] = acc;
            }
            __syncthreads();
        }
    }
    // final x2 in xb0; wlds[0]=k_w, wlds[1]=v_w

    // ---- show embeddings ----
    if (tid < NSHOW * EMB) {
        int s = tid >> 6, e = tid & 63;
        float acc = 0.f;
        #pragma unroll
        for (int i = 0; i < MSONG; i++) { int pm = pmap[s * MSONG + i]; if (pm >= 0) acc += xb0[pm][e]; }
        int cs = cnt_show[s];
        show_e[s][e] = (cs > 0) ? acc / (float)cs : 0.f;
    }
    __syncthreads();

    // ---- K, V from LDS-staged weights ----
    if (tid < 2 * NSHOW * EMB) {
        int m = (tid >= NSHOW * EMB) ? 1 : 0;
        int t = m ? tid - NSHOW * EMB : tid;
        int s = t >> 6, col = t & 63;
        float acc = m ? v_b[col] : k_b[col];
        #pragma unroll
        for (int e = 0; e < EMB; e++) acc += show_e[s][e] * wlds[m][e][col];
        if (m) vatt[s][col] = acc; else kvatt[s][col] = acc;
    }
    __syncthreads();

    // ---- scores (waves 0..4, wave reduce) ----
    if (wv < NSHOW) {
        float p = qv[lane] * kvatt[wv][lane];
        #pragma unroll
        for (int o = 32; o > 0; o >>= 1) p += __shfl_xor(p, o, 64);
        if (lane == 0) attnw[wv] = p * 0.125f;
    }
    __syncthreads();
    if (tid == 0) {
        float mx = attnw[0];
        for (int s = 1; s < NSHOW; s++) mx = fmaxf(mx, attnw[s]);
        float sum = 0.f;
        for (int s = 0; s < NSHOW; s++) { float ev = expf(attnw[s] - mx); attnw[s] = ev; sum += ev; }
        float isum = 1.f / sum;
        for (int s = 0; s < NSHOW; s++) attnw[s] *= isum;
    }
    __syncthreads();

    // ---- attended + concat ----
    if (tid < EMB) {
        float acc = 0.f;
        #pragma unroll
        for (int s = 0; s < NSHOW; s++) acc += attnw[s] * vatt[s][tid];
        hbuf[2 * EMB + tid] = acc;
        hbuf[EMB + tid]     = ctxv[tid];
        hbuf[tid]           = xb0[(int)idmap[sid]][tid];
    }
    __syncthreads();

    // ---- p1 (192->128): split-k 8-way, one batch of 24 coalesced loads/thread ----
    {
        int kk = tid >> 7, o = tid & 127;
        float acc = (kk == 0) ? p1_b[o] : 0.f;
        #pragma unroll
        for (int j = 0; j < 24; j++) { int e = kk * 24 + j; acc += hbuf[e] * p1_w[e * 128 + o]; }
        partial[kk * 128 + o] = acc;
    }
    __syncthreads();
    if (tid < 128) {
        float acc = 0.f;
        #pragma unroll
        for (int kk = 0; kk < 8; kk++) acc += partial[kk * 128 + tid];
        h1b[tid] = fmaxf(acc, 0.f);
    }
    __syncthreads();

    // ---- p2 (128->64): split-k 16-way ----
    {
        int kk = tid >> 6, o = lane;
        float acc = (kk == 0) ? p2_b[o] : 0.f;
        #pragma unroll
        for (int j = 0; j < 8; j++) { int e = kk * 8 + j; acc += h1b[e] * p2_w[e * 64 + o]; }
        partial[kk * 64 + o] = acc;
    }
    __syncthreads();
    if (tid < 64) {
        float acc = 0.f;
        #pragma unroll
        for (int kk = 0; kk < 16; kk++) acc += partial[kk * 64 + tid];
        h2b[tid] = fmaxf(acc, 0.f);
    }
    __syncthreads();

    // ---- p3 (64->1) + sigmoid: wave 0 reduce ----
    if (wv == 0) {
        float p3bias = p3_b[0];
        float p = h2b[lane] * p3_w[lane];
        #pragma unroll
        for (int o = 32; o > 0; o >>= 1) p += __shfl_xor(p, o, 64);
        if (lane == 0) out[b] = 1.f / (1.f + expf(-(p + p3bias)));
    }
}

extern "C" void kernel_launch(void* const* d_in, const int* in_sizes, int n_in,
                              void* d_out, int out_size, void* d_ws, size_t ws_size,
                              hipStream_t stream) {
    (void)n_in; (void)out_size; (void)d_ws; (void)ws_size;
    const int B = in_sizes[0];
    setsgnn_kernel<<<B, NT, 0, stream>>>(
        (const int*)d_in[0], (const int*)d_in[1], (const int*)d_in[2],
        (const int*)d_in[3], (const int*)d_in[4], (const int*)d_in[5],
        (const int*)d_in[6],
        (const float*)d_in[7],
        (const float*)d_in[8],  (const float*)d_in[9],
        (const float*)d_in[10], (const float*)d_in[11],
        (const float*)d_in[12], (const float*)d_in[13],
        (const float*)d_in[14], (const float*)d_in[15],
        (const float*)d_in[16], (const float*)d_in[17],
        (const float*)d_in[18], (const float*)d_in[19],
        (const float*)d_in[20], (const float*)d_in[21],
        (const float*)d_in[22],
        (const float*)d_in[23], (const float*)d_in[24],
        (const float*)d_in[25], (const float*)d_in[26],
        (const float*)d_in[27], (const float*)d_in[28],
        (const float*)d_in[29], (const float*)d_in[30],
        (float*)d_out);
}